// Round 8
// baseline (192.504 us; speedup 1.0000x reference)
//
#include <hip/hip_runtime.h>
#include <math.h>

#define BB 512
#define DD 512
#define KK 93431
#define KPAD 93440

#define S_SCALEf 64.0f
#define COS_Mf   0.87758256189037276f   /* cos(0.5) */
#define SIN_Mf   0.47942553860420301f   /* sin(0.5) */
#define THRESHf (-0.87758256189037276f) /* cos(pi-0.5) */
#define MMf      0.23971276930210151f   /* sin(pi-0.5)*0.5 */
#define EPSf     0.1f
#define MFIXf    65.0f

typedef __bf16 bf16x8 __attribute__((ext_vector_type(8)));
typedef float  f32x4  __attribute__((ext_vector_type(4)));
typedef unsigned short ushort8 __attribute__((ext_vector_type(8)));

__device__ __forceinline__ unsigned short f2bf(float f) {
    union { float f; unsigned u; } v; v.f = f;
    unsigned r = v.u + 0x7FFFu + ((v.u >> 16) & 1u);   // RNE
    return (unsigned short)(r >> 16);
}

__device__ __forceinline__ void gload16(const void* g, void* l) {
    __builtin_amdgcn_global_load_lds(
        (const __attribute__((address_space(1))) unsigned int*)g,
        (__attribute__((address_space(3))) unsigned int*)l, 16, 0, 0);
}

// ---------------- kernel 1: row-normalize x -> xn (f32) + xnb (bf16) ----------------
__global__ void rownorm_k(const float* __restrict__ x, float* __restrict__ xn,
                          unsigned short* __restrict__ xnb) {
    int b = blockIdx.x;
    int t = threadIdx.x; // 256
    float v0 = x[b * DD + t];
    float v1 = x[b * DD + t + 256];
    float ss = v0 * v0 + v1 * v1;
    for (int off = 32; off; off >>= 1) ss += __shfl_down(ss, off);
    __shared__ float wred[4];
    __shared__ float s_inv;
    if ((t & 63) == 0) wred[t >> 6] = ss;
    __syncthreads();
    if (t == 0) s_inv = rsqrtf(wred[0] + wred[1] + wred[2] + wred[3]);
    __syncthreads();
    float inv = s_inv;
    float a0 = v0 * inv, a1 = v1 * inv;
    xn[b * DD + t]        = a0;
    xn[b * DD + t + 256]  = a1;
    xnb[b * DD + t]       = f2bf(a0);
    xnb[b * DD + t + 256] = f2bf(a1);
}

// ------------- kernel 2: transpose+convert kernel matrix, partial column sumsq -------
__global__ __launch_bounds__(256) void tcvt_k(const float* __restrict__ ker,
                                              unsigned short* __restrict__ kerbt,
                                              float* __restrict__ ssq) {
    __shared__ float tile[64][65];
    __shared__ float sp[256];
    int t = threadIdx.x;
    int c0 = blockIdx.x * 64;
    int d0 = blockIdx.y * 64;
    int lc = t & 63;
    int dq = t >> 6;
    int gc = c0 + lc;
    bool valid = gc < KK;
    float ss = 0.f;
#pragma unroll
    for (int i = 0; i < 16; ++i) {
        int d = dq + i * 4;
        float v = valid ? ker[(size_t)(d0 + d) * KK + gc] : 0.f;
        tile[d][lc] = v;
        ss = fmaf(v, v, ss);
    }
    sp[t] = ss;
    __syncthreads();
    if (t < 64 && (c0 + t) < KK) {
        float tot = sp[t] + sp[t + 64] + sp[t + 128] + sp[t + 192];
        atomicAdd(&ssq[c0 + t], tot);
    }
#pragma unroll
    for (int j = 0; j < 2; ++j) {
        int l = t + 256 * j;
        int c = l >> 3;
        int dc = l & 7;
        ushort8 o;
#pragma unroll
        for (int e = 0; e < 8; ++e) o[e] = f2bf(tile[dc * 8 + e][c]);
        *reinterpret_cast<ushort8*>(&kerbt[(size_t)(c0 + c) * DD + d0 + dc * 8]) = o;
    }
}

// ---------------- kernel 3: target logits (label columns, fp32) ----------------
__global__ void target_k(const float* __restrict__ xn, const float* __restrict__ ker,
                         const float* __restrict__ ssq, const int* __restrict__ label,
                         float* __restrict__ tl) {
    int b = blockIdx.x;
    int lane = threadIdx.x; // 64
    int col = label[b];
    float acc = 0.f;
#pragma unroll
    for (int d = lane; d < DD; d += 64)
        acc = fmaf(xn[b * DD + d], ker[(size_t)d * KK + col], acc);
    for (int off = 32; off; off >>= 1) acc += __shfl_down(acc, off);
    if (lane == 0) {
        float c = acc * rsqrtf(ssq[col]);
        c = fminf(1.f, fmaxf(-1.f, c));
        tl[b] = c;
    }
}

// ------- kernel 4: scalars (t_new, cos_theta_m, final target) + ssq pad fix -------
__global__ void scalar_k(const float* __restrict__ tl, const float* __restrict__ t_in,
                         float* __restrict__ ctm, float* __restrict__ ftl,
                         float* __restrict__ tnew, float* __restrict__ ssq) {
    int t = threadIdx.x; // 512
    float v = tl[t];
    __shared__ float red[8];
    __shared__ float s_tn;
    float s = v;
    for (int off = 32; off; off >>= 1) s += __shfl_down(s, off);
    if ((t & 63) == 0) red[t >> 6] = s;
    __syncthreads();
    if (t == 0) {
        float tot = 0.f;
        for (int i = 0; i < 8; ++i) tot += red[i];
        s_tn = (tot / 512.0f) * 0.01f + 0.99f * t_in[0];
        tnew[0] = s_tn;
    }
    __syncthreads();
    float st = sqrtf(fmaxf(0.f, 1.f - v * v));
    float cm = v * COS_Mf - st * SIN_Mf;
    ctm[t] = cm;
    ftl[t] = (v > THRESHf) ? cm : (v - MMf);
    if (t < KPAD - KK) ssq[KK + t] = 1.f;   // pad cols: kerbt rows are 0 -> logit 0
}

// ---- kernel 5: 128x128 tiled MFMA GEMM, single-barrier 2-phase, hoisted addrs ----
// 512 thr = 8 waves (2 wm x 4 wn), wave = 64 rows x 32 cols, acc = 4x2 f32x4.
// LDS: 2x16KB A + 2x16KB B + ~3KB epilogue = 67KB -> 2 blocks/CU, 16 waves/CU.
#define TMt 128
#define TNt 128
#define BKt 64
#define NWG ((KPAD / TNt) * (BB / TMt))   /* 730 * 4 = 2920 */

__global__ __launch_bounds__(512) void gemm_k(
    const unsigned short* __restrict__ xnb,    // [512][512] bf16 row-major
    const unsigned short* __restrict__ kerbt,  // [KPAD][512] bf16 row-major
    const float* __restrict__ ssq,
    const int* __restrict__ label,
    const float* __restrict__ ctm, const float* __restrict__ ftl,
    const float* __restrict__ tnew,
    float* __restrict__ gse, float* __restrict__ gsl)
{
    __shared__ __align__(16) unsigned short As[2][TMt * BKt];  // 2 x 16 KB
    __shared__ __align__(16) unsigned short Bs[2][TNt * BKt];  // 2 x 16 KB
    __shared__ float se_s[TMt], sl_s[TMt], ctm_s[TMt], ftl_s[TMt];
    __shared__ int   lbl_s[TMt];

    // bijective XCD swizzle (2920 % 8 == 0); row-block-inner decomposition
    int wg = blockIdx.x;
    int id = (wg & 7) * (NWG / 8) + (wg >> 3);
    int by = id & 3;                   // 4 row-blocks of a col-tile adjacent
    int bx = id >> 2;
    int row0 = by * TMt;
    int col0 = bx * TNt;

    const int t = threadIdx.x;         // 512
    const int lane = t & 63;
    const int w = t >> 6;
    const int wm = w >> 2;             // 0..1  (64-row slice)
    const int wn = w & 3;              // 0..3  (32-col slice)
    const int cp0 = lane & 15;
    const int kq = lane >> 4;

    if (t < TMt) {
        se_s[t] = 0.f; sl_s[t] = 0.f;
        int r = row0 + t;
        ctm_s[t] = ctm[r]; ftl_s[t] = ftl[r]; lbl_s[t] = label[r];
    }
    const float tn = tnew[0];

    // prologue ssq loads (consumed only in epilogue)
    float sq2[2];
#pragma unroll
    for (int fc = 0; fc < 2; ++fc)
        sq2[fc] = ssq[col0 + wn * 32 + fc * 16 + cp0];

    // ---- hoisted per-thread staging geometry (advance by +128B per k-step) ----
    // A chunks: l = t, t+512; r = l>>3, kcs = (l&7)^(r&7).  Same form for B.
    const int lA0 = t,        rA0 = lA0 >> 3, kA0 = (lA0 & 7) ^ (rA0 & 7);
    const int lA1 = t + 512,  rA1 = lA1 >> 3, kA1 = (lA1 & 7) ^ (rA1 & 7);
    const char* pA0 = (const char*)&xnb[(size_t)(row0 + rA0) * DD + kA0 * 8];
    const char* pA1 = (const char*)&xnb[(size_t)(row0 + rA1) * DD + kA1 * 8];
    const char* pB0 = (const char*)&kerbt[(size_t)(col0 + rA0) * DD + kA0 * 8];
    const char* pB1 = (const char*)&kerbt[(size_t)(col0 + rA1) * DD + kA1 * 8];
    // LDS dests (per-buffer base folds to an immediate; l*16 bytes per chunk)
    unsigned short* dA0[2] = { &As[0][lA0 * 8], &As[1][lA0 * 8] };
    unsigned short* dA1[2] = { &As[0][lA1 * 8], &As[1][lA1 * 8] };
    unsigned short* dB0[2] = { &Bs[0][lA0 * 8], &Bs[1][lA0 * 8] };
    unsigned short* dB1[2] = { &Bs[0][lA1 * 8], &Bs[1][lA1 * 8] };

    // ---- hoisted LDS read offsets (bytes, buffer-relative) ----
    int offA[4][2], offB[2][2];
#pragma unroll
    for (int fm = 0; fm < 4; ++fm) {
        const int rt = wm * 64 + fm * 16 + cp0;
#pragma unroll
        for (int ks = 0; ks < 2; ++ks)
            offA[fm][ks] = rt * 128 + (((ks * 4 + kq) ^ (rt & 7)) * 16);
    }
#pragma unroll
    for (int fc = 0; fc < 2; ++fc) {
        const int ct = wn * 32 + fc * 16 + cp0;
#pragma unroll
        for (int ks = 0; ks < 2; ++ks)
            offB[fc][ks] = ct * 128 + (((ks * 4 + kq) ^ (ct & 7)) * 16);
    }

#define STAGE(bi)                                                              \
    {                                                                          \
        gload16(pA0, dA0[bi]); gload16(pA1, dA1[bi]);                          \
        gload16(pB0, dB0[bi]); gload16(pB1, dB1[bi]);                          \
        pA0 += 128; pA1 += 128; pB0 += 128; pB1 += 128;                        \
    }

    f32x4 acc[4][2];
#pragma unroll
    for (int fm = 0; fm < 4; ++fm)
#pragma unroll
        for (int fc = 0; fc < 2; ++fc) acc[fm][fc] = (f32x4)0.f;

    // ---- prologue: stage tile 0 -> buf 0 ----
    STAGE(0);
    __builtin_amdgcn_sched_barrier(0);
    asm volatile("s_waitcnt vmcnt(0)" ::: "memory");
    __builtin_amdgcn_s_barrier();

    // ---- main loop (fully unrolled): stage-early, ONE barrier per k-step ----
#pragma unroll
    for (int kt = 0; kt < 8; ++kt) {
        const int bi = kt & 1;
        if (kt < 7) STAGE(bi ^ 1);          // tile kt+1 -> other buffer (async)
        const char* Ap = (const char*)&As[bi][0];
        const char* Bp = (const char*)&Bs[bi][0];
#pragma unroll
        for (int ks = 0; ks < 2; ++ks) {
            bf16x8 bfr[2];
#pragma unroll
            for (int fc = 0; fc < 2; ++fc)
                bfr[fc] = *reinterpret_cast<const bf16x8*>(Bp + offB[fc][ks]);
#pragma unroll
            for (int fm = 0; fm < 4; ++fm) {
                bf16x8 af = *reinterpret_cast<const bf16x8*>(Ap + offA[fm][ks]);
                acc[fm][0] = __builtin_amdgcn_mfma_f32_16x16x32_bf16(
                    af, bfr[0], acc[fm][0], 0, 0, 0);
                acc[fm][1] = __builtin_amdgcn_mfma_f32_16x16x32_bf16(
                    af, bfr[1], acc[fm][1], 0, 0, 0);
            }
        }
        // tile kt+1's DMA (issued above, hidden under compute) must be visible
        // to ALL waves before anyone reads it next iteration.
        __builtin_amdgcn_sched_barrier(0);
        asm volatile("s_waitcnt vmcnt(0)" ::: "memory");
        __builtin_amdgcn_s_barrier();
    }
#undef STAGE

    // ---- fused CurricularFace epilogue (once per block, full-K acc) ----
    float inv2[2];
#pragma unroll
    for (int fc = 0; fc < 2; ++fc) inv2[fc] = rsqrtf(sq2[fc]);

#pragma unroll
    for (int fm = 0; fm < 4; ++fm) {
#pragma unroll
        for (int reg = 0; reg < 4; ++reg) {
            const int rt = wm * 64 + fm * 16 + (kq << 2) + reg;  // block-local row
            float cm = ctm_s[rt], ft = ftl_s[rt];
            const int rel = lbl_s[rt] - (col0 + wn * 32 + cp0);
            float se = 0.f, sl = 0.f;
#pragma unroll
            for (int fc = 0; fc < 2; ++fc) {
                float c = acc[fm][fc][reg] * inv2[fc];
                c = fminf(1.f, fmaxf(-1.f, c));
                float v = (c > cm) ? c * (tn + c) : c;
                if (rel == fc * 16) v = ft;
                float lg = S_SCALEf * v;
                se += __expf(lg - MFIXf);
                sl += lg;
            }
#pragma unroll
            for (int off = 8; off; off >>= 1) {
                se += __shfl_down(se, off, 16);
                sl += __shfl_down(sl, off, 16);
            }
            if (cp0 == 0) {
                atomicAdd(&se_s[rt], se);
                atomicAdd(&sl_s[rt], sl);
            }
        }
    }
    __syncthreads();
    if (t < TMt) {
        atomicAdd(&gse[row0 + t], se_s[t]);
        atomicAdd(&gsl[row0 + t], sl_s[t]);
    }
}

// ---------------- kernel 6: final loss ----------------
__global__ void loss_k(const float* __restrict__ gse, const float* __restrict__ gsl,
                       const float* __restrict__ ftl, float* __restrict__ out) {
    int t = threadIdx.x; // 512
    float lse = MFIXf + logf(gse[t]);
    float lbl_logit = S_SCALEf * ftl[t];
    float nll = (1.f - EPSf) * (lbl_logit - lse)
              + (EPSf / (float)KK) * (gsl[t] - (float)KK * lse);
    __shared__ float red[8];
    float s = nll;
    for (int off = 32; off; off >>= 1) s += __shfl_down(s, off);
    if ((t & 63) == 0) red[t >> 6] = s;
    __syncthreads();
    if (t == 0) {
        float tot = 0.f;
        for (int i = 0; i < 8; ++i) tot += red[i];
        out[0] = -(tot / 512.0f);
    }
}

extern "C" void kernel_launch(void* const* d_in, const int* in_sizes, int n_in,
                              void* d_out, int out_size, void* d_ws, size_t ws_size,
                              hipStream_t stream) {
    const float* x     = (const float*)d_in[0];
    const int*   label = (const int*)d_in[1];
    const float* ker   = (const float*)d_in[2];
    const float* t_in  = (const float*)d_in[3];
    float* out = (float*)d_out;

    float* ws   = (float*)d_ws;
    float* xn   = ws;                 // 262144 f32
    float* ssq  = xn + 262144;        // KPAD
    float* gse  = ssq + KPAD;         // 512
    float* gsl  = gse + 512;          // 512
    float* tl   = gsl + 512;          // 512
    float* ctm  = tl + 512;           // 512
    float* ftl  = ctm + 512;          // 512
    float* tnew = ftl + 512;          // 64
    unsigned short* xnb   = (unsigned short*)(tnew + 64);    // 262144 bf16
    unsigned short* kerbt = xnb + 262144;                    // KPAD*512 bf16

    hipMemsetAsync(ssq, 0, (KPAD + 1024) * sizeof(float), stream);

    rownorm_k<<<BB, 256, 0, stream>>>(x, xn, xnb);
    tcvt_k<<<dim3(KPAD / 64, DD / 64), 256, 0, stream>>>(ker, kerbt, ssq);
    target_k<<<BB, 64, 0, stream>>>(xn, ker, ssq, label, tl);
    scalar_k<<<1, 512, 0, stream>>>(tl, t_in, ctm, ftl, tnew, ssq);
    gemm_k<<<NWG, 512, 0, stream>>>(xnb, kerbt, ssq, label, ctm, ftl, tnew, gse, gsl);
    loss_k<<<1, 512, 0, stream>>>(gse, gsl, ftl, out);
}

// Round 9
// 169.773 us; speedup vs baseline: 1.1339x; 1.1339x over previous
//
#include <hip/hip_runtime.h>
#include <math.h>

#define BB 512
#define DD 512
#define KK 93431
#define KPAD 93440

#define S_SCALEf 64.0f
#define COS_Mf   0.87758256189037276f   /* cos(0.5) */
#define SIN_Mf   0.47942553860420301f   /* sin(0.5) */
#define THRESHf (-0.87758256189037276f) /* cos(pi-0.5) */
#define MMf      0.23971276930210151f   /* sin(pi-0.5)*0.5 */
#define EPSf     0.1f
#define MFIXf    65.0f

typedef __bf16 bf16x8 __attribute__((ext_vector_type(8)));
typedef float  f32x4  __attribute__((ext_vector_type(4)));
typedef unsigned short ushort8 __attribute__((ext_vector_type(8)));

__device__ __forceinline__ unsigned short f2bf(float f) {
    union { float f; unsigned u; } v; v.f = f;
    unsigned r = v.u + 0x7FFFu + ((v.u >> 16) & 1u);   // RNE
    return (unsigned short)(r >> 16);
}

__device__ __forceinline__ void gload16(const void* g, void* l) {
    __builtin_amdgcn_global_load_lds(
        (const __attribute__((address_space(1))) unsigned int*)g,
        (__attribute__((address_space(3))) unsigned int*)l, 16, 0, 0);
}

// ---------------- kernel 1: row-normalize x -> xn (f32) + xnb (bf16) ----------------
__global__ void rownorm_k(const float* __restrict__ x, float* __restrict__ xn,
                          unsigned short* __restrict__ xnb) {
    int b = blockIdx.x;
    int t = threadIdx.x; // 256
    float v0 = x[b * DD + t];
    float v1 = x[b * DD + t + 256];
    float ss = v0 * v0 + v1 * v1;
    for (int off = 32; off; off >>= 1) ss += __shfl_down(ss, off);
    __shared__ float wred[4];
    __shared__ float s_inv;
    if ((t & 63) == 0) wred[t >> 6] = ss;
    __syncthreads();
    if (t == 0) s_inv = rsqrtf(wred[0] + wred[1] + wred[2] + wred[3]);
    __syncthreads();
    float inv = s_inv;
    float a0 = v0 * inv, a1 = v1 * inv;
    xn[b * DD + t]        = a0;
    xn[b * DD + t + 256]  = a1;
    xnb[b * DD + t]       = f2bf(a0);
    xnb[b * DD + t + 256] = f2bf(a1);
}

// ------------- kernel 2: transpose+convert kernel matrix, partial column sumsq -------
__global__ __launch_bounds__(256) void tcvt_k(const float* __restrict__ ker,
                                              unsigned short* __restrict__ kerbt,
                                              float* __restrict__ ssq) {
    __shared__ float tile[64][65];
    __shared__ float sp[256];
    int t = threadIdx.x;
    int c0 = blockIdx.x * 64;
    int d0 = blockIdx.y * 64;
    int lc = t & 63;
    int dq = t >> 6;
    int gc = c0 + lc;
    bool valid = gc < KK;
    float ss = 0.f;
#pragma unroll
    for (int i = 0; i < 16; ++i) {
        int d = dq + i * 4;
        float v = valid ? ker[(size_t)(d0 + d) * KK + gc] : 0.f;
        tile[d][lc] = v;
        ss = fmaf(v, v, ss);
    }
    sp[t] = ss;
    __syncthreads();
    if (t < 64 && (c0 + t) < KK) {
        float tot = sp[t] + sp[t + 64] + sp[t + 128] + sp[t + 192];
        atomicAdd(&ssq[c0 + t], tot);
    }
#pragma unroll
    for (int j = 0; j < 2; ++j) {
        int l = t + 256 * j;
        int c = l >> 3;
        int dc = l & 7;
        ushort8 o;
#pragma unroll
        for (int e = 0; e < 8; ++e) o[e] = f2bf(tile[dc * 8 + e][c]);
        *reinterpret_cast<ushort8*>(&kerbt[(size_t)(c0 + c) * DD + d0 + dc * 8]) = o;
    }
}

// ---------------- kernel 3: target logits (label columns, fp32) ----------------
__global__ void target_k(const float* __restrict__ xn, const float* __restrict__ ker,
                         const float* __restrict__ ssq, const int* __restrict__ label,
                         float* __restrict__ tl) {
    int b = blockIdx.x;
    int lane = threadIdx.x; // 64
    int col = label[b];
    float acc = 0.f;
#pragma unroll
    for (int d = lane; d < DD; d += 64)
        acc = fmaf(xn[b * DD + d], ker[(size_t)d * KK + col], acc);
    for (int off = 32; off; off >>= 1) acc += __shfl_down(acc, off);
    if (lane == 0) {
        float c = acc * rsqrtf(ssq[col]);
        c = fminf(1.f, fmaxf(-1.f, c));
        tl[b] = c;
    }
}

// ------- kernel 4: scalars (t_new, cos_theta_m, final target) + ssq pad fix -------
__global__ void scalar_k(const float* __restrict__ tl, const float* __restrict__ t_in,
                         float* __restrict__ ctm, float* __restrict__ ftl,
                         float* __restrict__ tnew, float* __restrict__ ssq) {
    int t = threadIdx.x; // 512
    float v = tl[t];
    __shared__ float red[8];
    __shared__ float s_tn;
    float s = v;
    for (int off = 32; off; off >>= 1) s += __shfl_down(s, off);
    if ((t & 63) == 0) red[t >> 6] = s;
    __syncthreads();
    if (t == 0) {
        float tot = 0.f;
        for (int i = 0; i < 8; ++i) tot += red[i];
        s_tn = (tot / 512.0f) * 0.01f + 0.99f * t_in[0];
        tnew[0] = s_tn;
    }
    __syncthreads();
    float st = sqrtf(fmaxf(0.f, 1.f - v * v));
    float cm = v * COS_Mf - st * SIN_Mf;
    ctm[t] = cm;
    ftl[t] = (v > THRESHf) ? cm : (v - MMf);
    if (t < KPAD - KK) ssq[KK + t] = 1.f;   // pad cols: kerbt rows are 0 -> logit 0
}

// ---- kernel 5: 256x256 MFMA GEMM, quadrant-phase schedule (m201-style) ----
// 512 thr = 8 waves (2 wm x 4 wn); wave output = 128 rows x 64 cols.
// acc = 8x4 f32x4 (128 VGPR); JIT fragment reads per quadrant; 2 barriers/K-tile;
// counted vmcnt(8) (next tile landed, tile-after in flight). 1 block/CU (133KB LDS).
#define TM2 256
#define TN2 256
#define NCOL (KPAD / TN2)      /* 365 */
#define NWG2 (2 * NCOL)        /* 730 */

__global__ __launch_bounds__(512, 2) void gemm_k(
    const unsigned short* __restrict__ xnb,    // [512][512] bf16 row-major
    const unsigned short* __restrict__ kerbt,  // [KPAD][512] bf16 row-major
    const float* __restrict__ ssq,
    const int* __restrict__ label,
    const float* __restrict__ ctm, const float* __restrict__ ftl,
    const float* __restrict__ tnew,
    float* __restrict__ gse, float* __restrict__ gsl)
{
    __shared__ __align__(16) unsigned short As[2][TM2 * 64];  // 2 x 32 KB
    __shared__ __align__(16) unsigned short Bs[2][TN2 * 64];  // 2 x 32 KB
    __shared__ float se_s[TM2], sl_s[TM2], ctm_s[TM2], ftl_s[TM2];
    __shared__ int   lbl_s[TM2];

    // bijective XCD swizzle: 730 = 8*91 + 2 (m204 formula)
    int wg = blockIdx.x;
    int xcd = wg & 7, pos = wg >> 3;
    int id = (xcd < 2 ? xcd * 92 : 2 * 92 + (xcd - 2) * 91) + pos;
    int by = id & 1;                    // row-block inner: B-panel shared on XCD
    int bx = id >> 1;
    int row0 = by * TM2, col0 = bx * TN2;

    const int t = threadIdx.x;          // 512
    const int lane = t & 63;
    const int w = t >> 6;
    const int wm = w >> 2;              // 0..1  (128-row slice)
    const int wn = w & 3;               // 0..3  (64-col slice)
    const int cp0 = lane & 15;
    const int kq = lane >> 4;

    if (t < TM2) {
        se_s[t] = 0.f; sl_s[t] = 0.f;
        int r = row0 + t;
        ctm_s[t] = ctm[r]; ftl_s[t] = ftl[r]; lbl_s[t] = label[r];
    }
    const float tn = tnew[0];

    float sq4[4];
#pragma unroll
    for (int fc = 0; fc < 4; ++fc)
        sq4[fc] = ssq[col0 + wn * 64 + fc * 16 + cp0];

    // staging geometry: chunk l = t + 512*j (j=0..3): r = l>>3, kc = l&7.
    // (t&7) and ((t>>3)&7) invariant under +512j -> j adds exactly 64 rows = 65536 B.
    const int rA = t >> 3, kcA = (t & 7) ^ (rA & 7);
    const char* pAsrc = (const char*)&xnb[(size_t)(row0 + rA) * DD + kcA * 8];
    const char* pBsrc = (const char*)&kerbt[(size_t)(col0 + rA) * DD + kcA * 8];

#define STAGE2(ktv, bi)                                                        \
    {                                                                          \
        const char* sa = pAsrc + (ktv) * 128;                                  \
        const char* sb = pBsrc + (ktv) * 128;                                  \
        _Pragma("unroll")                                                      \
        for (int j = 0; j < 4; ++j)                                            \
            gload16(sa + j * 65536, (void*)&As[bi][(t + 512 * j) * 8]);        \
        _Pragma("unroll")                                                      \
        for (int j = 0; j < 4; ++j)                                            \
            gload16(sb + j * 65536, (void*)&Bs[bi][(t + 512 * j) * 8]);        \
    }

    // fragment read bases (byte offsets; fm/fc add imm*2048)
    const int swz0 = ((0 * 4 + kq) ^ (cp0 & 7)) * 16;
    const int swz1 = ((1 * 4 + kq) ^ (cp0 & 7)) * 16;
    const int aoff = (wm * 128 + cp0) * 128;
    const int boff = (wn * 64 + cp0) * 128;

    f32x4 acc[8][4];
#pragma unroll
    for (int fm = 0; fm < 8; ++fm)
#pragma unroll
        for (int fc = 0; fc < 4; ++fc) acc[fm][fc] = (f32x4)0.f;

    // ---- prologue: stage K-tiles 0 and 1 ----
    STAGE2(0, 0);
    STAGE2(1, 1);
    __builtin_amdgcn_sched_barrier(0);
    asm volatile("s_waitcnt vmcnt(8)" ::: "memory");   // tile 0 landed
    __builtin_amdgcn_s_barrier();

#pragma unroll
    for (int kt = 0; kt < 8; ++kt) {
        const int bi = kt & 1;
        const char* Ab = (const char*)&As[bi][0] + aoff;
        const char* Bb = (const char*)&Bs[bi][0] + boff;
        bf16x8 a0[4][2], a1[4][2], b0[2][2], b1[2][2];

        // ---- P1: read A0 (fm 0-3) + B0 (fc 0-1); MFMA q00 ----
#pragma unroll
        for (int fm = 0; fm < 4; ++fm) {
            a0[fm][0] = *reinterpret_cast<const bf16x8*>(Ab + fm * 2048 + swz0);
            a0[fm][1] = *reinterpret_cast<const bf16x8*>(Ab + fm * 2048 + swz1);
        }
#pragma unroll
        for (int fc = 0; fc < 2; ++fc) {
            b0[fc][0] = *reinterpret_cast<const bf16x8*>(Bb + fc * 2048 + swz0);
            b0[fc][1] = *reinterpret_cast<const bf16x8*>(Bb + fc * 2048 + swz1);
        }
        __builtin_amdgcn_s_setprio(1);
#pragma unroll
        for (int fm = 0; fm < 4; ++fm)
#pragma unroll
            for (int fc = 0; fc < 2; ++fc)
#pragma unroll
                for (int ks = 0; ks < 2; ++ks)
                    acc[fm][fc] = __builtin_amdgcn_mfma_f32_16x16x32_bf16(
                        a0[fm][ks], b0[fc][ks], acc[fm][fc], 0, 0, 0);
        __builtin_amdgcn_s_setprio(0);

        // ---- P2: read B1 (fc 2-3); MFMA q01 ----
#pragma unroll
        for (int fc = 0; fc < 2; ++fc) {
            b1[fc][0] = *reinterpret_cast<const bf16x8*>(Bb + (fc + 2) * 2048 + swz0);
            b1[fc][1] = *reinterpret_cast<const bf16x8*>(Bb + (fc + 2) * 2048 + swz1);
        }
        __builtin_amdgcn_s_setprio(1);
#pragma unroll
        for (int fm = 0; fm < 4; ++fm)
#pragma unroll
            for (int fc = 0; fc < 2; ++fc)
#pragma unroll
                for (int ks = 0; ks < 2; ++ks)
                    acc[fm][fc + 2] = __builtin_amdgcn_mfma_f32_16x16x32_bf16(
                        a0[fm][ks], b1[fc][ks], acc[fm][fc + 2], 0, 0, 0);
        __builtin_amdgcn_s_setprio(0);

        // ---- P3: read A1 (fm 4-7); drain reads; barrier; stage kt+2; MFMA q11 ----
#pragma unroll
        for (int fm = 0; fm < 4; ++fm) {
            a1[fm][0] = *reinterpret_cast<const bf16x8*>(Ab + (fm + 4) * 2048 + swz0);
            a1[fm][1] = *reinterpret_cast<const bf16x8*>(Ab + (fm + 4) * 2048 + swz1);
        }
        asm volatile("s_waitcnt lgkmcnt(0)" ::: "memory");  // my reads of buf done
        __builtin_amdgcn_s_barrier();                       // ALL waves' reads done
        if (kt + 2 < 8) STAGE2(kt + 2, bi);                 // safe to overwrite buf
        __builtin_amdgcn_s_setprio(1);
#pragma unroll
        for (int fm = 0; fm < 4; ++fm)
#pragma unroll
            for (int fc = 0; fc < 2; ++fc)
#pragma unroll
                for (int ks = 0; ks < 2; ++ks)
                    acc[fm + 4][fc + 2] = __builtin_amdgcn_mfma_f32_16x16x32_bf16(
                        a1[fm][ks], b1[fc][ks], acc[fm + 4][fc + 2], 0, 0, 0);
        __builtin_amdgcn_s_setprio(0);

        // ---- P4: MFMA q10; counted wait for tile kt+1; barrier ----
        __builtin_amdgcn_s_setprio(1);
#pragma unroll
        for (int fm = 0; fm < 4; ++fm)
#pragma unroll
            for (int fc = 0; fc < 2; ++fc)
#pragma unroll
                for (int ks = 0; ks < 2; ++ks)
                    acc[fm + 4][fc] = __builtin_amdgcn_mfma_f32_16x16x32_bf16(
                        a1[fm][ks], b0[fc][ks], acc[fm + 4][fc], 0, 0, 0);
        __builtin_amdgcn_s_setprio(0);
        if (kt + 2 < 8) {
            __builtin_amdgcn_sched_barrier(0);
            asm volatile("s_waitcnt vmcnt(8)" ::: "memory");  // kt+1 landed
        } else if (kt + 1 < 8) {
            __builtin_amdgcn_sched_barrier(0);
            asm volatile("s_waitcnt vmcnt(0)" ::: "memory");
        }
        if (kt + 1 < 8) __builtin_amdgcn_s_barrier();
    }
#undef STAGE2

    // ---- fused CurricularFace epilogue (once per block, full-K acc) ----
    float inv4[4];
#pragma unroll
    for (int fc = 0; fc < 4; ++fc) inv4[fc] = rsqrtf(sq4[fc]);

#pragma unroll
    for (int fm = 0; fm < 8; ++fm) {
#pragma unroll
        for (int reg = 0; reg < 4; ++reg) {
            const int rt = wm * 128 + fm * 16 + (kq << 2) + reg;  // block-local row
            float cm = ctm_s[rt], ft = ftl_s[rt];
            const int rel = lbl_s[rt] - (col0 + wn * 64 + cp0);
            float se = 0.f, sl = 0.f;
#pragma unroll
            for (int fc = 0; fc < 4; ++fc) {
                float c = acc[fm][fc][reg] * inv4[fc];
                c = fminf(1.f, fmaxf(-1.f, c));
                float v = (c > cm) ? c * (tn + c) : c;
                if (rel == fc * 16) v = ft;
                float lg = S_SCALEf * v;
                se += __expf(lg - MFIXf);
                sl += lg;
            }
#pragma unroll
            for (int off = 8; off; off >>= 1) {
                se += __shfl_down(se, off, 16);
                sl += __shfl_down(sl, off, 16);
            }
            if (cp0 == 0) {
                atomicAdd(&se_s[rt], se);
                atomicAdd(&sl_s[rt], sl);
            }
        }
    }
    __syncthreads();
    if (t < TM2) {
        atomicAdd(&gse[row0 + t], se_s[t]);
        atomicAdd(&gsl[row0 + t], sl_s[t]);
    }
}

// ---------------- kernel 6: final loss ----------------
__global__ void loss_k(const float* __restrict__ gse, const float* __restrict__ gsl,
                       const float* __restrict__ ftl, float* __restrict__ out) {
    int t = threadIdx.x; // 512
    float lse = MFIXf + logf(gse[t]);
    float lbl_logit = S_SCALEf * ftl[t];
    float nll = (1.f - EPSf) * (lbl_logit - lse)
              + (EPSf / (float)KK) * (gsl[t] - (float)KK * lse);
    __shared__ float red[8];
    float s = nll;
    for (int off = 32; off; off >>= 1) s += __shfl_down(s, off);
    if ((t & 63) == 0) red[t >> 6] = s;
    __syncthreads();
    if (t == 0) {
        float tot = 0.f;
        for (int i = 0; i < 8; ++i) tot += red[i];
        out[0] = -(tot / 512.0f);
    }
}

extern "C" void kernel_launch(void* const* d_in, const int* in_sizes, int n_in,
                              void* d_out, int out_size, void* d_ws, size_t ws_size,
                              hipStream_t stream) {
    const float* x     = (const float*)d_in[0];
    const int*   label = (const int*)d_in[1];
    const float* ker   = (const float*)d_in[2];
    const float* t_in  = (const float*)d_in[3];
    float* out = (float*)d_out;

    float* ws   = (float*)d_ws;
    float* xn   = ws;                 // 262144 f32
    float* ssq  = xn + 262144;        // KPAD
    float* gse  = ssq + KPAD;         // 512
    float* gsl  = gse + 512;          // 512
    float* tl   = gsl + 512;          // 512
    float* ctm  = tl + 512;           // 512
    float* ftl  = ctm + 512;          // 512
    float* tnew = ftl + 512;          // 64
    unsigned short* xnb   = (unsigned short*)(tnew + 64);    // 262144 bf16
    unsigned short* kerbt = xnb + 262144;                    // KPAD*512 bf16

    hipMemsetAsync(ssq, 0, (KPAD + 1024) * sizeof(float), stream);

    rownorm_k<<<BB, 256, 0, stream>>>(x, xn, xnb);
    tcvt_k<<<dim3(KPAD / 64, DD / 64), 256, 0, stream>>>(ker, kerbt, ssq);
    target_k<<<BB, 64, 0, stream>>>(xn, ker, ssq, label, tl);
    scalar_k<<<1, 512, 0, stream>>>(tl, t_in, ctm, ftl, tnew, ssq);
    gemm_k<<<NWG2, 512, 0, stream>>>(xnb, kerbt, ssq, label, ctm, ftl, tnew, gse, gsl);
    loss_k<<<1, 512, 0, stream>>>(gse, gsl, ftl, out);
}